// Round 5
// baseline (389.473 us; speedup 1.0000x reference)
//
#include <hip/hip_runtime.h>

// LiquidTimeConstantCell fused kernel, MI355X gfx950 — R11.
// Same MFMA layout / math as R8/R10 (transposed MFMA: C row = h, col = batch r,
// bf16 GEMM inputs, fp32 state). Geometry: 1024 thr / 16 waves, ROWS=64, grid=512.
// CHANGES vs R10 (attacking the 49%-VALU phase-lock, not occupancy):
//   1. ANTI-PHASED HALF-BLOCKS: the two 32-row groups (waves 0-7 / 8-15) get
//      private single-Y buffers and run half a stage out of phase: in each
//      barrier slot group A does feval (MFMA+LDS) while group B does the RK4
//      pointwise+store (VALU), then they swap. Barriers stay block-wide and
//      uniformly executed (2 per stage); each group's read/write ordering is
//      preserved by the cadence. Pipes overlap instead of taking turns.
//   2. VALU diet: xp1 = 1 + b_in + x@W_in^T persistent (folds tanh's "+1");
//      kv = fma(-2, rcp(1+exp2(2log2e*K)), xp1 - z)  -> 8 instr/elem, 2 TRANS.
//   3. LDS 70.1 -> 52.3 KB (two [32] single-Y replace the [64] double buffer).
//   4. __launch_bounds__(1024, 2): no spill risk; residency unchanged
//      (empirical law waves/CU ~ 2048/VGPR_total -> 16 waves either way).

constexpr int kB   = 32768;
constexpr int kH   = 128;
constexpr int kIn  = 128;
constexpr int kT   = 10;
constexpr int ROWS = 64;     // batch rows per block -> 512 blocks
constexpr int GR   = 32;     // rows per half-block group
constexpr int NT   = 2;      // row tiles per wave (32 rows)
constexpr int LDSW = 136;    // padded bf16 row stride
constexpr int HIN  = 256;    // H + IN

typedef __bf16 bf16;
typedef __attribute__((ext_vector_type(8))) __bf16 bf16x8;
typedef __attribute__((ext_vector_type(4))) __bf16 bf16x4;
typedef __attribute__((ext_vector_type(4))) float  f32x4;

__device__ __forceinline__ float sigmoid_(float v) {
  return __fdividef(1.0f, 1.0f + __expf(-v));
}

__device__ __forceinline__ bf16x8 cvt8(const float* p) {
  float4 f0 = *(const float4*)p;
  float4 f1 = *(const float4*)(p + 4);
  bf16x8 t;
  t[0]=(bf16)f0.x; t[1]=(bf16)f0.y; t[2]=(bf16)f0.z; t[3]=(bf16)f0.w;
  t[4]=(bf16)f1.x; t[5]=(bf16)f1.y; t[6]=(bf16)f1.z; t[7]=(bf16)f1.w;
  return t;
}

// C[nt] += bf16(Wb[hrow][kofs+k]) * S[rb + r][k];  hrow = hTile*16 + l16
// (A, m=l16), r = nt*16 + l16 (B, n=l16), k = kk*32 + quad*8 + j.
// S has >= rb+32 rows.
template <int SR>
__device__ __forceinline__ void gemm4(
    f32x4 (&C)[NT], const bf16 (*S)[LDSW],
    const float* __restrict__ Wb, int ldw, int kofs,
    int hTile, int rb, int quad, int l16)
{
#pragma unroll
  for (int kk = 0; kk < 4; ++kk) {
    bf16x8 af = cvt8(Wb + (size_t)(hTile*16 + l16) * ldw + kofs + kk*32 + quad*8);
#pragma unroll
    for (int nt = 0; nt < NT; ++nt) {
      bf16x8 bfv = *(const bf16x8*)&S[rb + nt*16 + l16][kk*32 + quad*8];
      C[nt] = __builtin_amdgcn_mfma_f32_16x16x32_bf16(af, bfv, C[nt], 0, 0, 0);
    }
  }
}

// K = bias + Weff @ z^T, z read from group-private Y (rows 0..31)
__device__ __forceinline__ void feval(
    f32x4 (&K)[NT], const bf16x8 (&weff)[4], const bf16 (*Y)[LDSW],
    float4 bv, int quad, int l16)
{
#pragma unroll
  for (int nt = 0; nt < NT; ++nt)
    K[nt] = f32x4{bv.x, bv.y, bv.z, bv.w};
#pragma unroll
  for (int kk = 0; kk < 4; ++kk)
#pragma unroll
    for (int nt = 0; nt < NT; ++nt) {
      bf16x8 bfv = *(const bf16x8*)&Y[nt*16 + l16][kk*32 + quad*8];
      K[nt] = __builtin_amdgcn_mfma_f32_16x16x32_bf16(weff[kk], bfv, K[nt], 0, 0, 0);
    }
}

// store V to group-private LDS Y[r][h] as bf16 (rows 0..31)
__device__ __forceinline__ void storeTileG(
    bf16 (*Y)[LDSW], const f32x4 (&V)[NT], int hc0, int l16)
{
#pragma unroll
  for (int nt = 0; nt < NT; ++nt) {
    bf16x4 p;
    p[0]=(bf16)V[nt][0]; p[1]=(bf16)V[nt][1];
    p[2]=(bf16)V[nt][2]; p[3]=(bf16)V[nt][3];
    *(bf16x4*)&Y[nt*16 + l16][hc0] = p;
  }
}

// store V to [ROWS]-row parking LDS at rbase offset
__device__ __forceinline__ void storeTile(
    bf16 (*Y)[LDSW], const f32x4 (&V)[NT], int hc0, int rbase, int l16)
{
#pragma unroll
  for (int nt = 0; nt < NT; ++nt) {
    bf16x4 p;
    p[0]=(bf16)V[nt][0]; p[1]=(bf16)V[nt][1];
    p[2]=(bf16)V[nt][2]; p[3]=(bf16)V[nt][3];
    *(bf16x4*)&Y[rbase + nt*16 + l16][hc0] = p;
  }
}

// store V to global fp32, row-major [r][h], gbase pre-offset to block rows
__device__ __forceinline__ void storeGlob(
    float* gbase, const f32x4 (&V)[NT], int hc0, int rbase, int l16)
{
#pragma unroll
  for (int nt = 0; nt < NT; ++nt) {
    float4 g{V[nt][0], V[nt][1], V[nt][2], V[nt][3]};
    *(float4*)(gbase + (size_t)(rbase + nt*16 + l16) * kH + hc0) = g;
  }
}

// RK4 pointwise for one sub-stage. kv = tanh(K) + xp - z with xp1 = 1 + xp:
// kv = (xp1 - z) - 2*rcp(1 + exp2(2log2e * K)).  sub is wave-uniform.
__device__ __forceinline__ void pw(
    int sub, float c6, float c3, float ch, float cd,
    const f32x4 (&K)[NT], const f32x4 (&xp1)[NT],
    f32x4 (&h)[NT], f32x4 (&z)[NT], f32x4 (&hacc)[NT])
{
#pragma unroll
  for (int nt = 0; nt < NT; ++nt)
#pragma unroll
    for (int i = 0; i < 4; ++i) {
      float m  = 2.8853900817779268f * K[nt][i];      // 2*log2(e) * K
      float e  = __builtin_amdgcn_exp2f(m);
      float r  = __builtin_amdgcn_rcpf(1.0f + e);
      float kv = __builtin_fmaf(-2.0f, r, xp1[nt][i] - z[nt][i]);
      if (sub == 0) {
        hacc[nt][i] = __builtin_fmaf(c6, kv, h[nt][i]);
        z[nt][i]    = __builtin_fmaf(ch, kv, h[nt][i]);
      } else if (sub == 1) {
        hacc[nt][i] = __builtin_fmaf(c3, kv, hacc[nt][i]);
        z[nt][i]    = __builtin_fmaf(ch, kv, h[nt][i]);
      } else if (sub == 2) {
        hacc[nt][i] = __builtin_fmaf(c3, kv, hacc[nt][i]);
        z[nt][i]    = __builtin_fmaf(cd, kv, h[nt][i]);
      } else {
        h[nt][i] = __builtin_fmaf(c6, kv, hacc[nt][i]);
        z[nt][i] = h[nt][i];
      }
    }
}

__global__ __launch_bounds__(1024, 2) void ltc_kernel(
    const float* __restrict__ x,     const float* __restrict__ hidden,
    const float* __restrict__ ts,    const float* __restrict__ wiring,
    const float* __restrict__ W,     const float* __restrict__ bb_,
    const float* __restrict__ W_in,  const float* __restrict__ b_in,
    const float* __restrict__ W_upd, const float* __restrict__ b_upd,
    const float* __restrict__ W_rst, const float* __restrict__ b_rst,
    float* __restrict__ out)   // FP32 output: [new_hidden (B,H); ode_out (T,B,H)]
{
  __shared__ bf16 ldsX [ROWS][LDSW];   // x tile; later h0 (bf16)
  __shared__ bf16 ldsHd[ROWS][LDSW];   // hidden tile; later u (bf16)
  __shared__ bf16 ldsYA[GR][LDSW];     // ODE state z, group A (rows 0..31)
  __shared__ bf16 ldsYB[GR][LDSW];     // ODE state z, group B (rows 32..63)
  __shared__ float sts[kT];

  const int tid   = threadIdx.x;
  const int wave  = tid >> 6;          // 0..15
  const int hTile = wave & 7;          // h-column tile (16 cols)
  const int grp   = wave >> 3;         // 0 = A (rows 0-31), 1 = B (rows 32-63)
  const int rbase = grp * GR;          // block-relative row offset
  const int lane  = tid & 63;
  const int quad  = lane >> 4;
  const int l16   = lane & 15;
  const int r0    = blockIdx.x * ROWS;
  const bool grpA = (grp == 0);

  if (tid < kT) sts[tid] = ts[tid];

  // ---- stage x & hidden tiles into LDS as bf16 (1024 threads, 64x32 float4) ----
#pragma unroll
  for (int i = 0; i < 2; ++i) {
    int idx = i*1024 + tid;           // float4 index in 64x32
    int row = idx >> 5;
    int c4  = (idx & 31) * 4;
    float4 vx = *(const float4*)(x      + (size_t)(r0+row)*kIn + c4);
    float4 vh = *(const float4*)(hidden + (size_t)(r0+row)*kH  + c4);
    bf16x4 bx; bx[0]=(bf16)vx.x; bx[1]=(bf16)vx.y; bx[2]=(bf16)vx.z; bx[3]=(bf16)vx.w;
    bf16x4 bh; bh[0]=(bf16)vh.x; bh[1]=(bf16)vh.y; bh[2]=(bf16)vh.z; bh[3]=(bf16)vh.w;
    *(bf16x4*)&ldsX [row][c4] = bx;
    *(bf16x4*)&ldsHd[row][c4] = bh;
  }

  const int hc0 = hTile*16 + quad*4;   // lane's C-tile h base (4 cols)

  // ---- persistent W_eff = W .* wiring, A-fragments (16 VGPRs) ----
  bf16x8 weff[4];
  {
    int hrow = hTile*16 + l16;
#pragma unroll
    for (int kk = 0; kk < 4; ++kk) {
      int k = kk*32 + quad*8;
      const float* wp = W      + (size_t)hrow*kH + k;
      const float* mp = wiring + (size_t)hrow*kH + k;
      float4 w0 = *(const float4*)wp, w1 = *(const float4*)(wp+4);
      float4 m0 = *(const float4*)mp, m1 = *(const float4*)(mp+4);
      bf16x8 t;
      t[0]=(bf16)(w0.x*m0.x); t[1]=(bf16)(w0.y*m0.y);
      t[2]=(bf16)(w0.z*m0.z); t[3]=(bf16)(w0.w*m0.w);
      t[4]=(bf16)(w1.x*m1.x); t[5]=(bf16)(w1.y*m1.y);
      t[6]=(bf16)(w1.z*m1.z); t[7]=(bf16)(w1.w*m1.w);
      weff[kk] = t;
    }
  }
  float4 bv = *(const float4*)(bb_ + hc0);

  __syncthreads();   // x/hidden tiles visible

  // ---- x_proj + 1 (persistent regs; the +1 folds tanh's "1-..." constant) ----
  f32x4 xp1[NT];
  {
    float4 bi = *(const float4*)(b_in + hc0);
#pragma unroll
    for (int nt = 0; nt < NT; ++nt)
      xp1[nt] = f32x4{bi.x + 1.0f, bi.y + 1.0f, bi.z + 1.0f, bi.w + 1.0f};
    gemm4<ROWS>(xp1, ldsX, W_in, kIn, 0, hTile, rbase, quad, l16);
  }

  // ---- both gates up front ----
  f32x4 h[NT], U[NT];
  {
    f32x4 R[NT];
    float4 br = *(const float4*)(b_rst + hc0);
    float4 bu = *(const float4*)(b_upd + hc0);
#pragma unroll
    for (int nt = 0; nt < NT; ++nt) {
      R[nt] = f32x4{br.x, br.y, br.z, br.w};
      U[nt] = f32x4{bu.x, bu.y, bu.z, bu.w};
    }
    gemm4<ROWS>(R, ldsHd, W_rst, HIN, 0,  hTile, rbase, quad, l16);
    gemm4<ROWS>(R, ldsX,  W_rst, HIN, kH, hTile, rbase, quad, l16);
    gemm4<ROWS>(U, ldsHd, W_upd, HIN, 0,  hTile, rbase, quad, l16);
    gemm4<ROWS>(U, ldsX,  W_upd, HIN, kH, hTile, rbase, quad, l16);

#pragma unroll
    for (int nt = 0; nt < NT; ++nt) {
      const float* hp = hidden + (size_t)(r0 + rbase + nt*16 + l16)*kH + hc0;
      float4 hv = *(const float4*)hp;
      h[nt][0] = sigmoid_(R[nt][0]) * hv.x;   // h0
      h[nt][1] = sigmoid_(R[nt][1]) * hv.y;
      h[nt][2] = sigmoid_(R[nt][2]) * hv.z;
      h[nt][3] = sigmoid_(R[nt][3]) * hv.w;
      U[nt][0] = sigmoid_(U[nt][0]);          // u
      U[nt][1] = sigmoid_(U[nt][1]);
      U[nt][2] = sigmoid_(U[nt][2]);
      U[nt][3] = sigmoid_(U[nt][3]);
    }
  }

  __syncthreads();   // gate GEMM reads of ldsX/ldsHd done -> tiles reusable

  // park u and h0 in the now-dead tiles (bf16), freeing registers for the loop
  storeTile(ldsHd, U, hc0, rbase, l16);
  storeTile(ldsX,  h, hc0, rbase, l16);

  bf16 (*Yg)[LDSW] = grpA ? ldsYA : ldsYB;   // group-private single Y
  storeTileG(Yg, h, hc0, l16);               // z = h0
  storeGlob(out + (size_t)kB*kH + (size_t)r0*kH, h, hc0, rbase, l16); // ode_out[0]

  f32x4 z[NT], hacc[NT], K[NT];
#pragma unroll
  for (int nt = 0; nt < NT; ++nt) z[nt] = h[nt];

  __syncthreads();   // h0 visible to group peers

  // ---- anti-phased RK4 loop: 36 stages, 2 barriers each.  In slot P1 group A
  // runs feval(i) while group B runs pointwise(i-1)+store; in P2 they swap.
  // Cadence guarantees per-group: store -> barrier -> peer read -> barrier ->
  // overwrite.  All barriers are block-wide and uniformly executed.
  float c6P=0.f, c3P=0.f, chP=0.f, cdP=0.f;
  int   subP=0, tP=0;
  float* odeAll = out + (size_t)kB*kH;       // ode_out base

  for (int i = 0; i < 36; ++i) {
    int t = (i >> 2) + 1, sub = i & 3;
    float dt = sts[t] - sts[t-1];
    float c6 = dt * (1.0f/6.0f);
    float c3 = dt * (1.0f/3.0f);
    float ch = 0.5f * dt;

    // ---- P1 ----
    if (grpA) {
      feval(K, weff, Yg, bv, quad, l16);
    } else if (i > 0) {
      pw(subP, c6P, c3P, chP, cdP, K, xp1, h, z, hacc);
      storeTileG(Yg, z, hc0, l16);
      if (subP == 3)
        storeGlob(odeAll + ((size_t)tP*kB + r0)*kH, h, hc0, rbase, l16);
    }
    __syncthreads();

    // ---- P2 ----
    if (grpA) {
      pw(sub, c6, c3, ch, dt, K, xp1, h, z, hacc);
      storeTileG(Yg, z, hc0, l16);
      if (sub == 3)
        storeGlob(odeAll + ((size_t)t*kB + r0)*kH, h, hc0, rbase, l16);
    } else {
      feval(K, weff, Yg, bv, quad, l16);
    }
    __syncthreads();

    c6P = c6; c3P = c3; chP = ch; cdP = dt; subP = sub; tP = t;
  }

  // group B epilogue: finish stage 35 (t=9, sub=3) and store ode_out[9]
  if (!grpA) {
    pw(subP, c6P, c3P, chP, cdP, K, xp1, h, z, hacc);
    storeGlob(odeAll + ((size_t)tP*kB + r0)*kH, h, hc0, rbase, l16);
  }

  // ---- final blend: new_hidden = u*h_last + (1-u)*h0 (fp32 store) ----
  // parked u/h0 rectangles were written by this same wave -> no barrier needed
#pragma unroll
  for (int nt = 0; nt < NT; ++nt) {
    int r = rbase + nt*16 + l16;
    bf16x4 uv  = *(const bf16x4*)&ldsHd[r][hc0];
    bf16x4 h0v = *(const bf16x4*)&ldsX [r][hc0];
    float4 p;
    {
      float uu;
      uu = (float)uv[0]; p.x = uu * h[nt][0] + (1.0f - uu) * (float)h0v[0];
      uu = (float)uv[1]; p.y = uu * h[nt][1] + (1.0f - uu) * (float)h0v[1];
      uu = (float)uv[2]; p.z = uu * h[nt][2] + (1.0f - uu) * (float)h0v[2];
      uu = (float)uv[3]; p.w = uu * h[nt][3] + (1.0f - uu) * (float)h0v[3];
    }
    *(float4*)(out + (size_t)(r0 + r) * kH + hc0) = p;
  }
}

extern "C" void kernel_launch(void* const* d_in, const int* in_sizes, int n_in,
                              void* d_out, int out_size, void* d_ws, size_t ws_size,
                              hipStream_t stream) {
  (void)d_ws; (void)ws_size; (void)out_size;
  // Resolve input order from in_sizes (insurance; documented order expected).
  int ix=0, ih=1, its=2, iwr=3, iW=4, ib=5, iWin=6, ibin=7, iWu=8, ibu=9, iWr=10, ibr=11;
  if (n_in == 12 && in_sizes[2] != 10 && in_sizes[5] == 10) {
    // case-insensitive name-sorted: b,b_in,b_rst,b_upd,hidden,time_span,W,W_in,W_rst,W_upd,wiring,x
    ib=0; ibin=1; ibr=2; ibu=3; ih=4; its=5; iW=6; iWin=7; iWr=8; iWu=9; iwr=10; ix=11;
  }
  const float* x      = (const float*)d_in[ix];
  const float* hidden = (const float*)d_in[ih];
  const float* ts     = (const float*)d_in[its];
  const float* wiring = (const float*)d_in[iwr];
  const float* W      = (const float*)d_in[iW];
  const float* b      = (const float*)d_in[ib];
  const float* W_in   = (const float*)d_in[iWin];
  const float* b_in   = (const float*)d_in[ibin];
  const float* W_upd  = (const float*)d_in[iWu];
  const float* b_upd  = (const float*)d_in[ibu];
  const float* W_rst  = (const float*)d_in[iWr];
  const float* b_rst  = (const float*)d_in[ibr];

  dim3 grid(kB / ROWS);   // 512 blocks
  dim3 block(1024);
  ltc_kernel<<<grid, block, 0, stream>>>(x, hidden, ts, wiring, W, b,
                                         W_in, b_in, W_upd, b_upd, W_rst, b_rst,
                                         (float*)d_out);
}